// Round 1
// baseline (15683.315 us; speedup 1.0000x reference)
//
#include <hip/hip_runtime.h>

#define NN 1024
#define NOPEN 128
#define NHID 256
#define NSTART 40
#define NCLOSE 3
#define NLAYERS 40
#define KSZ 9

static constexpr float H2 = 0.01f;     // h*h, h = 0.1
static constexpr float IN_EPS = 1e-5f; // instance norm eps

// ---------------- opening: Zc = Kopen @ Z ; Zold = Zc ----------------
__global__ void k_open(const float* __restrict__ Kopen, const float* __restrict__ Z,
                       float* __restrict__ Zc, float* __restrict__ Zold) {
    int n = blockIdx.x * 256 + threadIdx.x;
    int o = blockIdx.y;
    float acc = 0.f;
#pragma unroll
    for (int s = 0; s < NSTART; ++s)
        acc = fmaf(Kopen[o * NSTART + s], Z[s * NN + n], acc);
    Zc[o * NN + n] = acc;
    Zold[o * NN + n] = acc;
}

// ---------------- sq[i] = sum_c Zc[c,i]^2 ; zero sigma accumulator ----------------
__global__ void k_sq(const float* __restrict__ Zc, float* __restrict__ sq, float* __restrict__ sig) {
    int i = blockIdx.x * 256 + threadIdx.x;
    float a = 0.f;
    for (int c = 0; c < NOPEN; ++c) { float v = Zc[c * NN + i]; a = fmaf(v, v, a); }
    sq[i] = a;
    if (i == 0) sig[0] = 0.f;
}

// ---------------- D2 = max(sq_i + sq_j - 2 * Zc^T Zc, 0); accumulate sum(D2) ----------------
__global__ __launch_bounds__(256) void k_d2(const float* __restrict__ Zc, const float* __restrict__ sq,
                                            float* __restrict__ D2, float* __restrict__ sig) {
    __shared__ __align__(16) float Zi[32 * 36];
    __shared__ __align__(16) float Zj[32 * 68];
    __shared__ float red[4];
    const int tid = threadIdx.x;
    const int tx = tid & 15, ty = tid >> 4;
    const int j0 = blockIdx.x * 64, i0 = blockIdx.y * 32;
    float acc[2][4] = {};
    for (int c0 = 0; c0 < NOPEN; c0 += 32) {
        for (int idx = tid; idx < 32 * 32; idx += 256) {
            int c = idx >> 5, ii = idx & 31;
            Zi[c * 36 + ii] = Zc[(c0 + c) * NN + i0 + ii];
        }
        for (int idx = tid; idx < 32 * 64; idx += 256) {
            int c = idx >> 6, jj = idx & 63;
            Zj[c * 68 + jj] = Zc[(c0 + c) * NN + j0 + jj];
        }
        __syncthreads();
#pragma unroll 8
        for (int c = 0; c < 32; ++c) {
            float2 zi = *(const float2*)&Zi[c * 36 + ty * 2];
            float4 zj = *(const float4*)&Zj[c * 68 + tx * 4];
            acc[0][0] = fmaf(zi.x, zj.x, acc[0][0]);
            acc[0][1] = fmaf(zi.x, zj.y, acc[0][1]);
            acc[0][2] = fmaf(zi.x, zj.z, acc[0][2]);
            acc[0][3] = fmaf(zi.x, zj.w, acc[0][3]);
            acc[1][0] = fmaf(zi.y, zj.x, acc[1][0]);
            acc[1][1] = fmaf(zi.y, zj.y, acc[1][1]);
            acc[1][2] = fmaf(zi.y, zj.z, acc[1][2]);
            acc[1][3] = fmaf(zi.y, zj.w, acc[1][3]);
        }
        __syncthreads();
    }
    float part = 0.f;
#pragma unroll
    for (int m = 0; m < 2; ++m) {
        int i = i0 + ty * 2 + m;
        float sqi = sq[i];
        float4 d;
        d.x = fmaxf(sqi + sq[j0 + tx * 4 + 0] - 2.f * acc[m][0], 0.f);
        d.y = fmaxf(sqi + sq[j0 + tx * 4 + 1] - 2.f * acc[m][1], 0.f);
        d.z = fmaxf(sqi + sq[j0 + tx * 4 + 2] - 2.f * acc[m][2], 0.f);
        d.w = fmaxf(sqi + sq[j0 + tx * 4 + 3] - 2.f * acc[m][3], 0.f);
        *(float4*)&D2[(size_t)i * NN + j0 + tx * 4] = d;
        part += (d.x + d.y) + (d.z + d.w);
    }
#pragma unroll
    for (int off = 32; off > 0; off >>= 1) part += __shfl_down(part, off);
    if ((tid & 63) == 0) red[tid >> 6] = part;
    __syncthreads();
    if (tid == 0) atomicAdd(sig, red[0] + red[1] + red[2] + red[3]);
}

// ---------------- deg_i = sum_j exp(-D2_ij/sigma); Dh_i = rsqrt(deg_i) ----------------
__global__ void k_deg(const float* __restrict__ D2, const float* __restrict__ sig,
                      float* __restrict__ Dh) {
    __shared__ float red[4];
    int i = blockIdx.x, tid = threadIdx.x;
    float inv = 1.f / (sig[0] * (1.f / 1048576.f) + 1e-12f);
    float4 v = *(const float4*)&D2[(size_t)i * NN + tid * 4];
    float s = __expf(-v.x * inv) + __expf(-v.y * inv) + __expf(-v.z * inv) + __expf(-v.w * inv);
#pragma unroll
    for (int off = 32; off > 0; off >>= 1) s += __shfl_down(s, off);
    if ((tid & 63) == 0) red[tid >> 6] = s;
    __syncthreads();
    if (tid == 0) Dh[i] = rsqrtf(red[0] + red[1] + red[2] + red[3]);
}

// ---------------- L_ij = delta_ij - Dh_i * Dh_j * exp(-D2_ij/sigma) ----------------
__global__ void k_L(const float* __restrict__ D2, const float* __restrict__ sig,
                    const float* __restrict__ Dh, float* __restrict__ Lm) {
    int i = blockIdx.x, tid = threadIdx.x;
    int j = tid * 4;
    float inv = 1.f / (sig[0] * (1.f / 1048576.f) + 1e-12f);
    float dhi = Dh[i];
    float4 v = *(const float4*)&D2[(size_t)i * NN + j];
    float4 dj = *(const float4*)&Dh[j];
    float4 o;
    o.x = -dhi * dj.x * __expf(-v.x * inv);
    o.y = -dhi * dj.y * __expf(-v.y * inv);
    o.z = -dhi * dj.z * __expf(-v.z * inv);
    o.w = -dhi * dj.w * __expf(-v.w * inv);
    if (i == j + 0) o.x += 1.f;
    if (i == j + 1) o.y += 1.f;
    if (i == j + 2) o.z += 1.f;
    if (i == j + 3) o.w += 1.f;
    *(float4*)&Lm[(size_t)i * NN + j] = o;
}

// ---------------- dual conv1d: C[co,p] = sum_{ci,t} W[co,ci,t] * (Zc+B)[ci, p+t-4] ----------------
// grid (16 p-tiles, 8 co-tiles, 2 convs), block 256; tile 32co x 64p, thread 2co x 4p
__global__ __launch_bounds__(256) void k_conv(const float* __restrict__ Zc, const float* __restrict__ W,
                                              const float* __restrict__ B, float* __restrict__ C0,
                                              float* __restrict__ C1) {
    const int z = blockIdx.z;
    const float* Wz = W + z * (NHID * NOPEN * KSZ);
    const float* Bz = B + z * NOPEN;
    float* C = z ? C1 : C0;
    const int tid = threadIdx.x;
    const int tx = tid & 15, ty = tid >> 4;
    const int p0 = blockIdx.x * 64, co0 = blockIdx.y * 32;
    __shared__ __align__(16) float Xs[16 * 76];
    __shared__ float Ws[32 * 148];
    float acc[2][4] = {};
    for (int ci0 = 0; ci0 < NOPEN; ci0 += 16) {
        for (int idx = tid; idx < 16 * 72; idx += 256) {
            int ci = idx / 72, pp = idx - ci * 72;
            int gp = p0 - 4 + pp;
            float v = 0.f;
            if ((unsigned)gp < (unsigned)NN) v = Zc[(ci0 + ci) * NN + gp] + Bz[ci0 + ci];
            Xs[ci * 76 + pp] = v;
        }
        for (int idx = tid; idx < 32 * 144; idx += 256) {
            int co = idx / 144, r = idx - co * 144;
            Ws[co * 148 + r] = Wz[(co0 + co) * (NOPEN * KSZ) + ci0 * KSZ + r];
        }
        __syncthreads();
        for (int ci = 0; ci < 16; ++ci) {
            float xw[12];
            *(float4*)&xw[0] = *(const float4*)&Xs[ci * 76 + tx * 4];
            *(float4*)&xw[4] = *(const float4*)&Xs[ci * 76 + tx * 4 + 4];
            *(float4*)&xw[8] = *(const float4*)&Xs[ci * 76 + tx * 4 + 8];
#pragma unroll
            for (int m = 0; m < 2; ++m) {
                const float* wr = &Ws[(ty * 2 + m) * 148 + ci * 9];
                float wv[9];
#pragma unroll
                for (int t = 0; t < 9; ++t) wv[t] = wr[t];
#pragma unroll
                for (int t = 0; t < 9; ++t)
#pragma unroll
                    for (int p = 0; p < 4; ++p)
                        acc[m][p] = fmaf(wv[t], xw[p + t], acc[m][p]);
            }
        }
        __syncthreads();
    }
#pragma unroll
    for (int m = 0; m < 2; ++m) {
        float4 o = {acc[m][0], acc[m][1], acc[m][2], acc[m][3]};
        *(float4*)&C[(co0 + ty * 2 + m) * NN + p0 + tx * 4] = o;
    }
}

// ---------------- Out = X @ L (L symmetric); LEAP: fuse leapfrog epilogue ----------------
// grid (16 j-tiles, M/32 m-tiles), block 256; tile 32m x 64j, thread 2m x 4j
template <bool LEAP>
__global__ __launch_bounds__(256) void k_xl(const float* __restrict__ X, const float* __restrict__ Lm,
                                            float* __restrict__ Out, const float* __restrict__ T0,
                                            const float* __restrict__ Zc, float* __restrict__ Zold) {
    const int tid = threadIdx.x;
    const int tx = tid & 15, ty = tid >> 4;
    const int j0 = blockIdx.x * 64, m0 = blockIdx.y * 32;
    __shared__ __align__(16) float XsT[32 * 36];
    __shared__ __align__(16) float Ls[32 * 68];
    float acc[2][4] = {};
    for (int i0 = 0; i0 < NN; i0 += 32) {
        for (int idx = tid; idx < 32 * 32; idx += 256) {
            int mm = idx >> 5, ii = idx & 31;
            XsT[ii * 36 + mm] = X[(m0 + mm) * NN + i0 + ii];
        }
        for (int idx = tid; idx < 32 * 64; idx += 256) {
            int ii = idx >> 6, jj = idx & 63;
            Ls[ii * 68 + jj] = Lm[(size_t)(i0 + ii) * NN + j0 + jj];
        }
        __syncthreads();
#pragma unroll 8
        for (int ii = 0; ii < 32; ++ii) {
            float2 xv = *(const float2*)&XsT[ii * 36 + ty * 2];
            float4 lv = *(const float4*)&Ls[ii * 68 + tx * 4];
            acc[0][0] = fmaf(xv.x, lv.x, acc[0][0]);
            acc[0][1] = fmaf(xv.x, lv.y, acc[0][1]);
            acc[0][2] = fmaf(xv.x, lv.z, acc[0][2]);
            acc[0][3] = fmaf(xv.x, lv.w, acc[0][3]);
            acc[1][0] = fmaf(xv.y, lv.x, acc[1][0]);
            acc[1][1] = fmaf(xv.y, lv.y, acc[1][1]);
            acc[1][2] = fmaf(xv.y, lv.z, acc[1][2]);
            acc[1][3] = fmaf(xv.y, lv.w, acc[1][3]);
        }
        __syncthreads();
    }
    if (!LEAP) {
#pragma unroll
        for (int m = 0; m < 2; ++m) {
            float4 o = {acc[m][0], acc[m][1], acc[m][2], acc[m][3]};
            *(float4*)&Out[(m0 + ty * 2 + m) * NN + j0 + tx * 4] = o;
        }
    } else {
#pragma unroll
        for (int m = 0; m < 2; ++m) {
            int c = m0 + ty * 2 + m;
            int p = j0 + tx * 4;
            float4 t0 = *(const float4*)&T0[c * NN + p];
            float4 zc = *(const float4*)&Zc[c * NN + p];
            float4 zo = *(const float4*)&Zold[c * NN + p];
            float4 zn;
            zn.x = 2.f * zc.x - zo.x - H2 * (t0.x + acc[m][0]);
            zn.y = 2.f * zc.y - zo.y - H2 * (t0.y + acc[m][1]);
            zn.z = 2.f * zc.z - zo.z - H2 * (t0.z + acc[m][2]);
            zn.w = 2.f * zc.w - zo.w - H2 * (t0.w + acc[m][3]);
            *(float4*)&Zold[c * NN + p] = zn;
        }
    }
}

// ---------------- instance norm (biased var) + relu, in place; grid (256 ch, 2 bufs) ----------------
__global__ void k_inorm(float* __restrict__ C0, float* __restrict__ G1) {
    float* X = blockIdx.y ? G1 : C0;
    const int c = blockIdx.x, tid = threadIdx.x;
    __shared__ float rs[4], rq[4];
    __shared__ float stats[2];
    float4 v = *(const float4*)&X[c * NN + tid * 4];
    float s = (v.x + v.y) + (v.z + v.w);
    float q = (v.x * v.x + v.y * v.y) + (v.z * v.z + v.w * v.w);
#pragma unroll
    for (int off = 32; off > 0; off >>= 1) { s += __shfl_down(s, off); q += __shfl_down(q, off); }
    if ((tid & 63) == 0) { rs[tid >> 6] = s; rq[tid >> 6] = q; }
    __syncthreads();
    if (tid == 0) {
        float S = rs[0] + rs[1] + rs[2] + rs[3];
        float Q = rq[0] + rq[1] + rq[2] + rq[3];
        float mean = S * (1.f / NN);
        float var = Q * (1.f / NN) - mean * mean;
        stats[0] = mean;
        stats[1] = rsqrtf(var + IN_EPS);
    }
    __syncthreads();
    float mean = stats[0], scale = stats[1];
    float4 o;
    o.x = fmaxf((v.x - mean) * scale, 0.f);
    o.y = fmaxf((v.y - mean) * scale, 0.f);
    o.z = fmaxf((v.z - mean) * scale, 0.f);
    o.w = fmaxf((v.w - mean) * scale, 0.f);
    *(float4*)&X[c * NN + tid * 4] = o;
}

// ---------------- dual conv_transpose1d: T[ci,p] = sum_{co,t} W[co,ci,t] * A[co, p+4-t] ----------------
// grid (16 p-tiles, 4 ci-tiles, 2), block 256; tile 32ci x 64p, thread 2ci x 4p
__global__ __launch_bounds__(256) void k_convT(const float* __restrict__ A0, const float* __restrict__ A1,
                                               const float* __restrict__ W, float* __restrict__ T0,
                                               float* __restrict__ T1) {
    const int z = blockIdx.z;
    const float* A = z ? A1 : A0;
    const float* Wz = W + z * (NHID * NOPEN * KSZ);
    float* T = z ? T1 : T0;
    const int tid = threadIdx.x;
    const int tx = tid & 15, ty = tid >> 4;
    const int p0 = blockIdx.x * 64, ci0 = blockIdx.y * 32;
    __shared__ __align__(16) float As[16 * 76];
    __shared__ float Ws2[16 * 292];
    float acc[2][4] = {};
    for (int co0 = 0; co0 < NHID; co0 += 16) {
        for (int idx = tid; idx < 16 * 72; idx += 256) {
            int cc = idx / 72, pp = idx - cc * 72;
            int gp = p0 - 4 + pp;
            float v = 0.f;
            if ((unsigned)gp < (unsigned)NN) v = A[(co0 + cc) * NN + gp];
            As[cc * 76 + pp] = v;
        }
        for (int idx = tid; idx < 16 * 288; idx += 256) {
            int cc = idx / 288, r = idx - cc * 288;
            Ws2[cc * 292 + r] = Wz[(co0 + cc) * (NOPEN * KSZ) + ci0 * KSZ + r];
        }
        __syncthreads();
        for (int cc = 0; cc < 16; ++cc) {
            float xw[12];
            *(float4*)&xw[0] = *(const float4*)&As[cc * 76 + tx * 4];
            *(float4*)&xw[4] = *(const float4*)&As[cc * 76 + tx * 4 + 4];
            *(float4*)&xw[8] = *(const float4*)&As[cc * 76 + tx * 4 + 8];
#pragma unroll
            for (int m = 0; m < 2; ++m) {
                const float* wr = &Ws2[cc * 292 + (ty * 2 + m) * 9];
                float wv[9];
#pragma unroll
                for (int t = 0; t < 9; ++t) wv[t] = wr[t];
#pragma unroll
                for (int t = 0; t < 9; ++t)
#pragma unroll
                    for (int p = 0; p < 4; ++p)
                        acc[m][p] = fmaf(wv[t], xw[p + 8 - t], acc[m][p]);
            }
        }
        __syncthreads();
    }
#pragma unroll
    for (int m = 0; m < 2; ++m) {
        float4 o = {acc[m][0], acc[m][1], acc[m][2], acc[m][3]};
        *(float4*)&T[(ci0 + ty * 2 + m) * NN + p0 + tx * 4] = o;
    }
}

// ---------------- closing: out = concat(Kclose @ Zc, Kclose @ Zold) ----------------
__global__ void k_close(const float* __restrict__ Kclose, const float* __restrict__ Zc,
                        const float* __restrict__ Zold, float* __restrict__ out) {
    int n = blockIdx.x * 256 + threadIdx.x;
    int o = blockIdx.y;
    const float* Zb = blockIdx.z ? Zold : Zc;
    float a = 0.f;
#pragma unroll
    for (int c = 0; c < NOPEN; ++c) a = fmaf(Kclose[o * NOPEN + c], Zb[c * NN + n], a);
    out[blockIdx.z * (NCLOSE * NN) + o * NN + n] = a;
}

extern "C" void kernel_launch(void* const* d_in, const int* in_sizes, int n_in,
                              void* d_out, int out_size, void* d_ws, size_t ws_size,
                              hipStream_t stream) {
    const float* Z      = (const float*)d_in[0];
    const float* Kopen  = (const float*)d_in[1];
    const float* Kclose = (const float*)d_in[2];
    const float* W      = (const float*)d_in[3];
    const float* Bias   = (const float*)d_in[4];
    float* out = (float*)d_out;
    float* ws  = (float*)d_ws;

    // workspace layout (floats)
    float* Zb0 = ws + 0;        // 128*1024
    float* Zb1 = ws + 131072;   // 128*1024
    float* Lm  = ws + 262144;   // 1024*1024
    float* D2  = ws + 1310720;  // 1024*1024
    float* C0  = ws + 2359296;  // 256*1024
    float* C1  = ws + 2621440;  // 256*1024
    float* G1  = ws + 2883584;  // 256*1024
    float* T0  = ws + 3145728;  // 128*1024
    float* T1  = ws + 3276800;  // 128*1024
    float* sq  = ws + 3407872;  // 1024
    float* Dh  = ws + 3408896;  // 1024
    float* sig = ws + 3409920;  // 1

    k_open<<<dim3(4, NOPEN), 256, 0, stream>>>(Kopen, Z, Zb0, Zb1);

    float* Zc = Zb0;
    float* Zold = Zb1;
    for (int i = 0; i < NLAYERS; ++i) {
        if (i % 10 == 0) {
            k_sq<<<dim3(4), 256, 0, stream>>>(Zc, sq, sig);
            k_d2<<<dim3(16, 32), 256, 0, stream>>>(Zc, sq, D2, sig);
            k_deg<<<dim3(NN), 256, 0, stream>>>(D2, sig, Dh);
            k_L<<<dim3(NN), 256, 0, stream>>>(D2, sig, Dh, Lm);
        }
        const float* Wl = W + (size_t)i * 2 * NHID * NOPEN * KSZ;
        const float* Bl = Bias + (size_t)i * 2 * NOPEN;

        k_conv<<<dim3(16, 8, 2), 256, 0, stream>>>(Zc, Wl, Bl, C0, C1);
        k_xl<false><<<dim3(16, 8), 256, 0, stream>>>(C1, Lm, G1, nullptr, nullptr, nullptr);
        k_inorm<<<dim3(NHID, 2), 256, 0, stream>>>(C0, G1);                 // C0 -> A0, G1 -> A1
        k_convT<<<dim3(16, 4, 2), 256, 0, stream>>>(C0, G1, Wl, T0, T1);
        k_xl<true><<<dim3(16, 4), 256, 0, stream>>>(T1, Lm, nullptr, T0, Zc, Zold); // writes Znew into Zold
        float* tmp = Zc; Zc = Zold; Zold = tmp;
    }

    k_close<<<dim3(4, NCLOSE, 2), 256, 0, stream>>>(Kclose, Zc, Zold, out);
}

// Round 2
// 7525.086 us; speedup vs baseline: 2.0841x; 2.0841x over previous
//
#include <hip/hip_runtime.h>

#define NN 1024
#define NOPEN 128
#define NHID 256
#define NSTART 40
#define NCLOSE 3
#define NLAYERS 40
#define KSZ 9

static constexpr float H2 = 0.01f;     // h*h, h = 0.1
static constexpr float IN_EPS = 1e-5f; // instance norm eps

using floatx4 = __attribute__((ext_vector_type(4))) float;
using bfrag = __attribute__((ext_vector_type(8))) short; // 8 bf16 = 4 VGPRs

__device__ inline ushort f2bf(float f) {
    union { float f; unsigned u; } v; v.f = f;
    unsigned r = v.u + 0x7fffu + ((v.u >> 16) & 1u); // RNE
    return (ushort)(r >> 16);
}

// ---------------- opening: Zc = Kopen @ Z ; Zold = Zc ----------------
__global__ void k_open(const float* __restrict__ Kopen, const float* __restrict__ Z,
                       float* __restrict__ Zc, float* __restrict__ Zold) {
    int n = blockIdx.x * 256 + threadIdx.x;
    int o = blockIdx.y;
    float acc = 0.f;
#pragma unroll
    for (int s = 0; s < NSTART; ++s)
        acc = fmaf(Kopen[o * NSTART + s], Z[s * NN + n], acc);
    Zc[o * NN + n] = acc;
    Zold[o * NN + n] = acc;
}

// ---------------- sq[i] = sum_c Zc[c,i]^2 ; zero sigma accumulator ----------------
__global__ void k_sq(const float* __restrict__ Zc, float* __restrict__ sq, float* __restrict__ sig) {
    int i = blockIdx.x * 256 + threadIdx.x;
    float a = 0.f;
    for (int c = 0; c < NOPEN; ++c) { float v = Zc[c * NN + i]; a = fmaf(v, v, a); }
    sq[i] = a;
    if (i == 0) sig[0] = 0.f;
}

// ---------------- D2 = max(sq_i + sq_j - 2 * Zc^T Zc, 0); accumulate sum(D2) ----------------
__global__ __launch_bounds__(256) void k_d2(const float* __restrict__ Zc, const float* __restrict__ sq,
                                            float* __restrict__ D2, float* __restrict__ sig) {
    __shared__ __align__(16) float Zi[32 * 36];
    __shared__ __align__(16) float Zj[32 * 68];
    __shared__ float red[4];
    const int tid = threadIdx.x;
    const int tx = tid & 15, ty = tid >> 4;
    const int j0 = blockIdx.x * 64, i0 = blockIdx.y * 32;
    float acc[2][4] = {};
    for (int c0 = 0; c0 < NOPEN; c0 += 32) {
        for (int idx = tid; idx < 32 * 32; idx += 256) {
            int c = idx >> 5, ii = idx & 31;
            Zi[c * 36 + ii] = Zc[(c0 + c) * NN + i0 + ii];
        }
        for (int idx = tid; idx < 32 * 64; idx += 256) {
            int c = idx >> 6, jj = idx & 63;
            Zj[c * 68 + jj] = Zc[(c0 + c) * NN + j0 + jj];
        }
        __syncthreads();
#pragma unroll 8
        for (int c = 0; c < 32; ++c) {
            float2 zi = *(const float2*)&Zi[c * 36 + ty * 2];
            float4 zj = *(const float4*)&Zj[c * 68 + tx * 4];
            acc[0][0] = fmaf(zi.x, zj.x, acc[0][0]);
            acc[0][1] = fmaf(zi.x, zj.y, acc[0][1]);
            acc[0][2] = fmaf(zi.x, zj.z, acc[0][2]);
            acc[0][3] = fmaf(zi.x, zj.w, acc[0][3]);
            acc[1][0] = fmaf(zi.y, zj.x, acc[1][0]);
            acc[1][1] = fmaf(zi.y, zj.y, acc[1][1]);
            acc[1][2] = fmaf(zi.y, zj.z, acc[1][2]);
            acc[1][3] = fmaf(zi.y, zj.w, acc[1][3]);
        }
        __syncthreads();
    }
    float part = 0.f;
#pragma unroll
    for (int m = 0; m < 2; ++m) {
        int i = i0 + ty * 2 + m;
        float sqi = sq[i];
        float4 d;
        d.x = fmaxf(sqi + sq[j0 + tx * 4 + 0] - 2.f * acc[m][0], 0.f);
        d.y = fmaxf(sqi + sq[j0 + tx * 4 + 1] - 2.f * acc[m][1], 0.f);
        d.z = fmaxf(sqi + sq[j0 + tx * 4 + 2] - 2.f * acc[m][2], 0.f);
        d.w = fmaxf(sqi + sq[j0 + tx * 4 + 3] - 2.f * acc[m][3], 0.f);
        *(float4*)&D2[(size_t)i * NN + j0 + tx * 4] = d;
        part += (d.x + d.y) + (d.z + d.w);
    }
#pragma unroll
    for (int off = 32; off > 0; off >>= 1) part += __shfl_down(part, off);
    if ((tid & 63) == 0) red[tid >> 6] = part;
    __syncthreads();
    if (tid == 0) atomicAdd(sig, red[0] + red[1] + red[2] + red[3]);
}

// ---------------- deg_i = sum_j exp(-D2_ij/sigma); Dh_i = rsqrt(deg_i) ----------------
__global__ void k_deg(const float* __restrict__ D2, const float* __restrict__ sig,
                      float* __restrict__ Dh) {
    __shared__ float red[4];
    int i = blockIdx.x, tid = threadIdx.x;
    float inv = 1.f / (sig[0] * (1.f / 1048576.f) + 1e-12f);
    float4 v = *(const float4*)&D2[(size_t)i * NN + tid * 4];
    float s = __expf(-v.x * inv) + __expf(-v.y * inv) + __expf(-v.z * inv) + __expf(-v.w * inv);
#pragma unroll
    for (int off = 32; off > 0; off >>= 1) s += __shfl_down(s, off);
    if ((tid & 63) == 0) red[tid >> 6] = s;
    __syncthreads();
    if (tid == 0) Dh[i] = rsqrtf(red[0] + red[1] + red[2] + red[3]);
}

// ---------------- Lb_ij = bf16( delta_ij - Dh_i * Dh_j * exp(-D2_ij/sigma) ) ----------------
__global__ void k_L(const float* __restrict__ D2, const float* __restrict__ sig,
                    const float* __restrict__ Dh, ushort* __restrict__ Lb) {
    int i = blockIdx.x, tid = threadIdx.x;
    int j = tid * 4;
    float inv = 1.f / (sig[0] * (1.f / 1048576.f) + 1e-12f);
    float dhi = Dh[i];
    float4 v = *(const float4*)&D2[(size_t)i * NN + j];
    float4 dj = *(const float4*)&Dh[j];
    float4 o;
    o.x = -dhi * dj.x * __expf(-v.x * inv);
    o.y = -dhi * dj.y * __expf(-v.y * inv);
    o.z = -dhi * dj.z * __expf(-v.z * inv);
    o.w = -dhi * dj.w * __expf(-v.w * inv);
    if (i == j + 0) o.x += 1.f;
    if (i == j + 1) o.y += 1.f;
    if (i == j + 2) o.z += 1.f;
    if (i == j + 3) o.w += 1.f;
    ushort4 ob; ob.x = f2bf(o.x); ob.y = f2bf(o.y); ob.z = f2bf(o.z); ob.w = f2bf(o.w);
    *(ushort4*)&Lb[(size_t)i * NN + j] = ob;
}

// ---------------- dual conv1d: C[co,p] = sum_{ci,t} W[co,ci,t] * (Zc+B)[ci, p+t-4] ----------------
// z=0 -> C0 (fp32, feeds inorm); z=1 -> C1b (bf16, feeds XL1 MFMA)
__global__ __launch_bounds__(256) void k_conv(const float* __restrict__ Zc, const float* __restrict__ W,
                                              const float* __restrict__ B, float* __restrict__ C0,
                                              ushort* __restrict__ C1b) {
    const int z = blockIdx.z;
    const float* Wz = W + z * (NHID * NOPEN * KSZ);
    const float* Bz = B + z * NOPEN;
    const int tid = threadIdx.x;
    const int tx = tid & 15, ty = tid >> 4;
    const int p0 = blockIdx.x * 64, co0 = blockIdx.y * 32;
    __shared__ __align__(16) float Xs[16 * 76];
    __shared__ float Ws[32 * 148];
    float acc[2][4] = {};
    for (int ci0 = 0; ci0 < NOPEN; ci0 += 16) {
        for (int idx = tid; idx < 16 * 72; idx += 256) {
            int ci = idx / 72, pp = idx - ci * 72;
            int gp = p0 - 4 + pp;
            float v = 0.f;
            if ((unsigned)gp < (unsigned)NN) v = Zc[(ci0 + ci) * NN + gp] + Bz[ci0 + ci];
            Xs[ci * 76 + pp] = v;
        }
        for (int idx = tid; idx < 32 * 144; idx += 256) {
            int co = idx / 144, r = idx - co * 144;
            Ws[co * 148 + r] = Wz[(co0 + co) * (NOPEN * KSZ) + ci0 * KSZ + r];
        }
        __syncthreads();
        for (int ci = 0; ci < 16; ++ci) {
            float xw[12];
            *(float4*)&xw[0] = *(const float4*)&Xs[ci * 76 + tx * 4];
            *(float4*)&xw[4] = *(const float4*)&Xs[ci * 76 + tx * 4 + 4];
            *(float4*)&xw[8] = *(const float4*)&Xs[ci * 76 + tx * 4 + 8];
#pragma unroll
            for (int m = 0; m < 2; ++m) {
                const float* wr = &Ws[(ty * 2 + m) * 148 + ci * 9];
                float wv[9];
#pragma unroll
                for (int t = 0; t < 9; ++t) wv[t] = wr[t];
#pragma unroll
                for (int t = 0; t < 9; ++t)
#pragma unroll
                    for (int p = 0; p < 4; ++p)
                        acc[m][p] = fmaf(wv[t], xw[p + t], acc[m][p]);
            }
        }
        __syncthreads();
    }
#pragma unroll
    for (int m = 0; m < 2; ++m) {
        if (z == 0) {
            float4 o = {acc[m][0], acc[m][1], acc[m][2], acc[m][3]};
            *(float4*)&C0[(co0 + ty * 2 + m) * NN + p0 + tx * 4] = o;
        } else {
            ushort4 o; o.x = f2bf(acc[m][0]); o.y = f2bf(acc[m][1]);
            o.z = f2bf(acc[m][2]); o.w = f2bf(acc[m][3]);
            *(ushort4*)&C1b[(co0 + ty * 2 + m) * NN + p0 + tx * 4] = o;
        }
    }
}

// ---------------- MFMA split-K GEMM: P[s] = X[:, sKc:(s+1)Kc] @ L[sKc:(s+1)Kc, :] ----------------
// X: M x 1024 bf16; Lb symmetric 1024x1024 bf16 (B[k][n] = L[n][k], read rows of L transpose-free).
// block 256 thr = 4 waves (2m x 2n), wave tile 32m x 64n, block tile 64m x 128n, Kc = 128.
// grid: (1024/128 = 8 n-tiles, M/64 m-tiles, 8 splits). Single barrier per block.
__global__ __launch_bounds__(256) void k_xl_mfma(const ushort* __restrict__ X,
                                                 const ushort* __restrict__ Lb,
                                                 float* __restrict__ P, int M) {
    __shared__ __align__(16) ushort As[64 * 136];
    __shared__ __align__(16) ushort Bs[128 * 136];
    const int tid = threadIdx.x;
    const int lane = tid & 63, wave = tid >> 6;
    const int wm = wave >> 1, wn = wave & 1;
    const int n0 = blockIdx.x * 128, m0 = blockIdx.y * 64, kc = blockIdx.z * 128;
    // stage A tile: 64 rows x 128 bf16 (4 x b128 per thread)
    {
        int q = tid;
#pragma unroll
        for (int r = 0; r < 4; ++r, q += 256) {
            int row = q >> 4, ch = (q & 15) * 8;
            *(bfrag*)&As[row * 136 + ch] = *(const bfrag*)&X[(m0 + row) * NN + kc + ch];
        }
        // stage B tile: 128 rows x 128 bf16 from L rows n0..n0+127 (symmetry), 8 x b128 per thread
        q = tid;
#pragma unroll
        for (int r = 0; r < 8; ++r, q += 256) {
            int row = q >> 4, ch = (q & 15) * 8;
            *(bfrag*)&Bs[row * 136 + ch] = *(const bfrag*)&Lb[(n0 + row) * NN + kc + ch];
        }
    }
    __syncthreads();
    floatx4 acc[2][4] = {};
    const int lrow = (lane & 15) * 136;      // fragment row select
    const int koff = (lane >> 4) * 8;        // fragment k select (quad*8)
#pragma unroll
    for (int ks = 0; ks < 4; ++ks) {
        bfrag a[2], b[4];
#pragma unroll
        for (int i = 0; i < 2; ++i)
            a[i] = *(const bfrag*)&As[(wm * 32 + i * 16) * 136 + lrow + ks * 32 + koff];
#pragma unroll
        for (int j = 0; j < 4; ++j)
            b[j] = *(const bfrag*)&Bs[(wn * 64 + j * 16) * 136 + lrow + ks * 32 + koff];
#pragma unroll
        for (int i = 0; i < 2; ++i)
#pragma unroll
            for (int j = 0; j < 4; ++j)
                acc[i][j] = __builtin_amdgcn_mfma_f32_16x16x32_bf16(a[i], b[j], acc[i][j], 0, 0, 0);
    }
    // C/D layout: row = (lane>>4)*4 + r, col = lane&15  [verified m89/m91]
    const int mg0 = m0 + wm * 32 + (lane >> 4) * 4;
    const int ng0 = n0 + wn * 64 + (lane & 15);
    const size_t base = (size_t)blockIdx.z * M * NN;
#pragma unroll
    for (int i = 0; i < 2; ++i)
#pragma unroll
        for (int j = 0; j < 4; ++j)
#pragma unroll
            for (int r = 0; r < 4; ++r)
                P[base + (size_t)(mg0 + i * 16 + r) * NN + ng0 + j * 16] = acc[i][j][r];
}

// ---------------- instance norm + relu ----------------
// y=0: in-place on C0 (fp32). y=1: sum 8 XL1 partials -> norm -> G1 (fp32).
__global__ void k_inorm(float* __restrict__ C0, const float* __restrict__ P1,
                        float* __restrict__ G1) {
    const int c = blockIdx.x, tid = threadIdx.x;
    __shared__ float rs[4], rq[4];
    __shared__ float stats[2];
    float4 v;
    if (blockIdx.y == 0) {
        v = *(const float4*)&C0[c * NN + tid * 4];
    } else {
        v.x = v.y = v.z = v.w = 0.f;
#pragma unroll
        for (int s = 0; s < 8; ++s) {
            float4 p = *(const float4*)&P1[(size_t)(s * NHID + c) * NN + tid * 4];
            v.x += p.x; v.y += p.y; v.z += p.z; v.w += p.w;
        }
    }
    float s = (v.x + v.y) + (v.z + v.w);
    float q = (v.x * v.x + v.y * v.y) + (v.z * v.z + v.w * v.w);
#pragma unroll
    for (int off = 32; off > 0; off >>= 1) { s += __shfl_down(s, off); q += __shfl_down(q, off); }
    if ((tid & 63) == 0) { rs[tid >> 6] = s; rq[tid >> 6] = q; }
    __syncthreads();
    if (tid == 0) {
        float S = rs[0] + rs[1] + rs[2] + rs[3];
        float Q = rq[0] + rq[1] + rq[2] + rq[3];
        float mean = S * (1.f / NN);
        float var = Q * (1.f / NN) - mean * mean;
        stats[0] = mean;
        stats[1] = rsqrtf(var + IN_EPS);
    }
    __syncthreads();
    float mean = stats[0], scale = stats[1];
    float4 o;
    o.x = fmaxf((v.x - mean) * scale, 0.f);
    o.y = fmaxf((v.y - mean) * scale, 0.f);
    o.z = fmaxf((v.z - mean) * scale, 0.f);
    o.w = fmaxf((v.w - mean) * scale, 0.f);
    if (blockIdx.y == 0) *(float4*)&C0[c * NN + tid * 4] = o;
    else                 *(float4*)&G1[c * NN + tid * 4] = o;
}

// ---------------- dual conv_transpose1d: T[ci,p] = sum_{co,t} W[co,ci,t] * A[co, p+4-t] ----------------
// z=0 -> T0 (fp32, feeds leapfrog); z=1 -> T1b (bf16, feeds XL2 MFMA)
__global__ __launch_bounds__(256) void k_convT(const float* __restrict__ A0, const float* __restrict__ A1,
                                               const float* __restrict__ W, float* __restrict__ T0,
                                               ushort* __restrict__ T1b) {
    const int z = blockIdx.z;
    const float* A = z ? A1 : A0;
    const float* Wz = W + z * (NHID * NOPEN * KSZ);
    const int tid = threadIdx.x;
    const int tx = tid & 15, ty = tid >> 4;
    const int p0 = blockIdx.x * 64, ci0 = blockIdx.y * 32;
    __shared__ __align__(16) float As[16 * 76];
    __shared__ float Ws2[16 * 292];
    float acc[2][4] = {};
    for (int co0 = 0; co0 < NHID; co0 += 16) {
        for (int idx = tid; idx < 16 * 72; idx += 256) {
            int cc = idx / 72, pp = idx - cc * 72;
            int gp = p0 - 4 + pp;
            float v = 0.f;
            if ((unsigned)gp < (unsigned)NN) v = A[(co0 + cc) * NN + gp];
            As[cc * 76 + pp] = v;
        }
        for (int idx = tid; idx < 16 * 288; idx += 256) {
            int cc = idx / 288, r = idx - cc * 288;
            Ws2[cc * 292 + r] = Wz[(co0 + cc) * (NOPEN * KSZ) + ci0 * KSZ + r];
        }
        __syncthreads();
        for (int cc = 0; cc < 16; ++cc) {
            float xw[12];
            *(float4*)&xw[0] = *(const float4*)&As[cc * 76 + tx * 4];
            *(float4*)&xw[4] = *(const float4*)&As[cc * 76 + tx * 4 + 4];
            *(float4*)&xw[8] = *(const float4*)&As[cc * 76 + tx * 4 + 8];
#pragma unroll
            for (int m = 0; m < 2; ++m) {
                const float* wr = &Ws2[cc * 292 + (ty * 2 + m) * 9];
                float wv[9];
#pragma unroll
                for (int t = 0; t < 9; ++t) wv[t] = wr[t];
#pragma unroll
                for (int t = 0; t < 9; ++t)
#pragma unroll
                    for (int p = 0; p < 4; ++p)
                        acc[m][p] = fmaf(wv[t], xw[p + 8 - t], acc[m][p]);
            }
        }
        __syncthreads();
    }
#pragma unroll
    for (int m = 0; m < 2; ++m) {
        if (z == 0) {
            float4 o = {acc[m][0], acc[m][1], acc[m][2], acc[m][3]};
            *(float4*)&T0[(ci0 + ty * 2 + m) * NN + p0 + tx * 4] = o;
        } else {
            ushort4 o; o.x = f2bf(acc[m][0]); o.y = f2bf(acc[m][1]);
            o.z = f2bf(acc[m][2]); o.w = f2bf(acc[m][3]);
            *(ushort4*)&T1b[(ci0 + ty * 2 + m) * NN + p0 + tx * 4] = o;
        }
    }
}

// ---------------- leapfrog: Znew = 2 Zc - Zold - h^2 (T0 + sum_s P2[s]); writes into Zold ----------------
__global__ void k_leap(const float* __restrict__ P2, const float* __restrict__ T0,
                       const float* __restrict__ Zc, float* __restrict__ Zold) {
    int off = (blockIdx.x * 256 + threadIdx.x) * 4; // over 128*1024 floats
    float4 a = *(const float4*)&T0[off];
#pragma unroll
    for (int s = 0; s < 8; ++s) {
        float4 p = *(const float4*)&P2[(size_t)(s << 17) + off];
        a.x += p.x; a.y += p.y; a.z += p.z; a.w += p.w;
    }
    float4 zc = *(const float4*)&Zc[off];
    float4 zo = *(const float4*)&Zold[off];
    float4 zn;
    zn.x = 2.f * zc.x - zo.x - H2 * a.x;
    zn.y = 2.f * zc.y - zo.y - H2 * a.y;
    zn.z = 2.f * zc.z - zo.z - H2 * a.z;
    zn.w = 2.f * zc.w - zo.w - H2 * a.w;
    *(float4*)&Zold[off] = zn;
}

// ---------------- closing: out = concat(Kclose @ Zc, Kclose @ Zold) ----------------
__global__ void k_close(const float* __restrict__ Kclose, const float* __restrict__ Zc,
                        const float* __restrict__ Zold, float* __restrict__ out) {
    int n = blockIdx.x * 256 + threadIdx.x;
    int o = blockIdx.y;
    const float* Zb = blockIdx.z ? Zold : Zc;
    float a = 0.f;
#pragma unroll
    for (int c = 0; c < NOPEN; ++c) a = fmaf(Kclose[o * NOPEN + c], Zb[c * NN + n], a);
    out[blockIdx.z * (NCLOSE * NN) + o * NN + n] = a;
}

extern "C" void kernel_launch(void* const* d_in, const int* in_sizes, int n_in,
                              void* d_out, int out_size, void* d_ws, size_t ws_size,
                              hipStream_t stream) {
    const float* Z      = (const float*)d_in[0];
    const float* Kopen  = (const float*)d_in[1];
    const float* Kclose = (const float*)d_in[2];
    const float* W      = (const float*)d_in[3];
    const float* Bias   = (const float*)d_in[4];
    float* out = (float*)d_out;
    float* ws  = (float*)d_ws;

    // workspace layout (float units)
    float* Zb0 = ws + 0;          // 131072
    float* Zb1 = ws + 131072;     // 131072
    float* D2  = ws + 262144;     // 1048576
    float* C0  = ws + 1310720;    // 262144
    float* G1  = ws + 1572864;    // 262144
    float* T0  = ws + 1835008;    // 131072
    float* P1  = ws + 1966080;    // 8*256*1024 = 2097152
    float* P2  = ws + 4063232;    // 8*128*1024 = 1048576
    float* sq  = ws + 5111808;    // 1024
    float* Dh  = ws + 5112832;    // 1024
    float* sig = ws + 5113856;    // 1024 (1 used)
    ushort* Lb  = (ushort*)(ws + 5114880); // 1024*1024 ushort
    ushort* C1b = (ushort*)(ws + 5639168); // 256*1024 ushort
    ushort* T1b = (ushort*)(ws + 5770240); // 128*1024 ushort

    k_open<<<dim3(4, NOPEN), 256, 0, stream>>>(Kopen, Z, Zb0, Zb1);

    float* Zc = Zb0;
    float* Zold = Zb1;
    for (int i = 0; i < NLAYERS; ++i) {
        if (i % 10 == 0) {
            k_sq<<<dim3(4), 256, 0, stream>>>(Zc, sq, sig);
            k_d2<<<dim3(16, 32), 256, 0, stream>>>(Zc, sq, D2, sig);
            k_deg<<<dim3(NN), 256, 0, stream>>>(D2, sig, Dh);
            k_L<<<dim3(NN), 256, 0, stream>>>(D2, sig, Dh, Lb);
        }
        const float* Wl = W + (size_t)i * 2 * NHID * NOPEN * KSZ;
        const float* Bl = Bias + (size_t)i * 2 * NOPEN;

        k_conv<<<dim3(16, 8, 2), 256, 0, stream>>>(Zc, Wl, Bl, C0, C1b);
        k_xl_mfma<<<dim3(8, 4, 8), 256, 0, stream>>>(C1b, Lb, P1, NHID);  // XL1: 256x1024
        k_inorm<<<dim3(NHID, 2), 256, 0, stream>>>(C0, P1, G1);           // C0->A0 (inplace), G1=A1
        k_convT<<<dim3(16, 4, 2), 256, 0, stream>>>(C0, G1, Wl, T0, T1b);
        k_xl_mfma<<<dim3(8, 2, 8), 256, 0, stream>>>(T1b, Lb, P2, NOPEN); // XL2: 128x1024
        k_leap<<<dim3(128), 256, 0, stream>>>(P2, T0, Zc, Zold);          // Znew -> Zold buffer
        float* tmp = Zc; Zc = Zold; Zold = tmp;
    }

    k_close<<<dim3(4, NCLOSE, 2), 256, 0, stream>>>(Kclose, Zc, Zold, out);
}

// Round 3
// 2238.453 us; speedup vs baseline: 7.0063x; 3.3617x over previous
//
#include <hip/hip_runtime.h>

#define NN 1024
#define NOPEN 128
#define NHID 256
#define NSTART 40
#define NCLOSE 3
#define NLAYERS 40
#define KSZ 9

static constexpr float H2 = 0.01f;     // h*h, h = 0.1
static constexpr float IN_EPS = 1e-5f; // instance norm eps

using floatx4 = __attribute__((ext_vector_type(4))) float;
using bfrag = __attribute__((ext_vector_type(8))) short; // 8 bf16 = 4 VGPRs

__device__ inline ushort f2bf(float f) {
    union { float f; unsigned u; } v; v.f = f;
    unsigned r = v.u + 0x7fffu + ((v.u >> 16) & 1u); // RNE
    return (ushort)(r >> 16);
}

// ---------------- opening: Zc = Kopen @ Z ; Zold = Zc ----------------
__global__ void k_open(const float* __restrict__ Kopen, const float* __restrict__ Z,
                       float* __restrict__ Zc, float* __restrict__ Zold) {
    int n = blockIdx.x * 256 + threadIdx.x;
    int o = blockIdx.y;
    float acc = 0.f;
#pragma unroll
    for (int s = 0; s < NSTART; ++s)
        acc = fmaf(Kopen[o * NSTART + s], Z[s * NN + n], acc);
    Zc[o * NN + n] = acc;
    Zold[o * NN + n] = acc;
}

// ---------------- sq[i] = sum_c Zc[c,i]^2 ; zero sigma accumulator ----------------
__global__ void k_sq(const float* __restrict__ Zc, float* __restrict__ sq, float* __restrict__ sig) {
    int i = blockIdx.x * 256 + threadIdx.x;
    float a = 0.f;
    for (int c = 0; c < NOPEN; ++c) { float v = Zc[c * NN + i]; a = fmaf(v, v, a); }
    sq[i] = a;
    if (i == 0) sig[0] = 0.f;
}

// ---------------- D2 = max(sq_i + sq_j - 2 * Zc^T Zc, 0); accumulate sum(D2) ----------------
__global__ __launch_bounds__(256) void k_d2(const float* __restrict__ Zc, const float* __restrict__ sq,
                                            float* __restrict__ D2, float* __restrict__ sig) {
    __shared__ __align__(16) float Zi[32 * 36];
    __shared__ __align__(16) float Zj[32 * 68];
    __shared__ float red[4];
    const int tid = threadIdx.x;
    const int tx = tid & 15, ty = tid >> 4;
    const int j0 = blockIdx.x * 64, i0 = blockIdx.y * 32;
    float acc[2][4] = {};
    for (int c0 = 0; c0 < NOPEN; c0 += 32) {
        for (int idx = tid; idx < 32 * 32; idx += 256) {
            int c = idx >> 5, ii = idx & 31;
            Zi[c * 36 + ii] = Zc[(c0 + c) * NN + i0 + ii];
        }
        for (int idx = tid; idx < 32 * 64; idx += 256) {
            int c = idx >> 6, jj = idx & 63;
            Zj[c * 68 + jj] = Zc[(c0 + c) * NN + j0 + jj];
        }
        __syncthreads();
#pragma unroll 8
        for (int c = 0; c < 32; ++c) {
            float2 zi = *(const float2*)&Zi[c * 36 + ty * 2];
            float4 zj = *(const float4*)&Zj[c * 68 + tx * 4];
            acc[0][0] = fmaf(zi.x, zj.x, acc[0][0]);
            acc[0][1] = fmaf(zi.x, zj.y, acc[0][1]);
            acc[0][2] = fmaf(zi.x, zj.z, acc[0][2]);
            acc[0][3] = fmaf(zi.x, zj.w, acc[0][3]);
            acc[1][0] = fmaf(zi.y, zj.x, acc[1][0]);
            acc[1][1] = fmaf(zi.y, zj.y, acc[1][1]);
            acc[1][2] = fmaf(zi.y, zj.z, acc[1][2]);
            acc[1][3] = fmaf(zi.y, zj.w, acc[1][3]);
        }
        __syncthreads();
    }
    float part = 0.f;
#pragma unroll
    for (int m = 0; m < 2; ++m) {
        int i = i0 + ty * 2 + m;
        float sqi = sq[i];
        float4 d;
        d.x = fmaxf(sqi + sq[j0 + tx * 4 + 0] - 2.f * acc[m][0], 0.f);
        d.y = fmaxf(sqi + sq[j0 + tx * 4 + 1] - 2.f * acc[m][1], 0.f);
        d.z = fmaxf(sqi + sq[j0 + tx * 4 + 2] - 2.f * acc[m][2], 0.f);
        d.w = fmaxf(sqi + sq[j0 + tx * 4 + 3] - 2.f * acc[m][3], 0.f);
        *(float4*)&D2[(size_t)i * NN + j0 + tx * 4] = d;
        part += (d.x + d.y) + (d.z + d.w);
    }
#pragma unroll
    for (int off = 32; off > 0; off >>= 1) part += __shfl_down(part, off);
    if ((tid & 63) == 0) red[tid >> 6] = part;
    __syncthreads();
    if (tid == 0) atomicAdd(sig, red[0] + red[1] + red[2] + red[3]);
}

// ---------------- deg_i = sum_j exp(-D2_ij/sigma); Dh_i = rsqrt(deg_i) ----------------
__global__ void k_deg(const float* __restrict__ D2, const float* __restrict__ sig,
                      float* __restrict__ Dh) {
    __shared__ float red[4];
    int i = blockIdx.x, tid = threadIdx.x;
    float inv = 1.f / (sig[0] * (1.f / 1048576.f) + 1e-12f);
    float4 v = *(const float4*)&D2[(size_t)i * NN + tid * 4];
    float s = __expf(-v.x * inv) + __expf(-v.y * inv) + __expf(-v.z * inv) + __expf(-v.w * inv);
#pragma unroll
    for (int off = 32; off > 0; off >>= 1) s += __shfl_down(s, off);
    if ((tid & 63) == 0) red[tid >> 6] = s;
    __syncthreads();
    if (tid == 0) Dh[i] = rsqrtf(red[0] + red[1] + red[2] + red[3]);
}

// ---------------- Lb_ij = bf16( delta_ij - Dh_i * Dh_j * exp(-D2_ij/sigma) ) ----------------
__global__ void k_L(const float* __restrict__ D2, const float* __restrict__ sig,
                    const float* __restrict__ Dh, ushort* __restrict__ Lb) {
    int i = blockIdx.x, tid = threadIdx.x;
    int j = tid * 4;
    float inv = 1.f / (sig[0] * (1.f / 1048576.f) + 1e-12f);
    float dhi = Dh[i];
    float4 v = *(const float4*)&D2[(size_t)i * NN + j];
    float4 dj = *(const float4*)&Dh[j];
    float4 o;
    o.x = -dhi * dj.x * __expf(-v.x * inv);
    o.y = -dhi * dj.y * __expf(-v.y * inv);
    o.z = -dhi * dj.z * __expf(-v.z * inv);
    o.w = -dhi * dj.w * __expf(-v.w * inv);
    if (i == j + 0) o.x += 1.f;
    if (i == j + 1) o.y += 1.f;
    if (i == j + 2) o.z += 1.f;
    if (i == j + 3) o.w += 1.f;
    ushort4 ob; ob.x = f2bf(o.x); ob.y = f2bf(o.y); ob.z = f2bf(o.z); ob.w = f2bf(o.w);
    *(ushort4*)&Lb[(size_t)i * NN + j] = ob;
}

// ---------------- per-layer prep: Zct (transposed, biased, padded), Wt, WtT (bf16) ----------------
// blocks 0..31: Zct[z][pos+4][ci]  (z*16 + ptile)
// blocks 32..103: Wt[z][t][co][ci]
// blocks 104..175: WtT[z][t][ci][co]
__global__ __launch_bounds__(256) void k_prep(const float* __restrict__ Zc,
        const float* __restrict__ W, const float* __restrict__ B,
        ushort* __restrict__ Zct, ushort* __restrict__ Wt, ushort* __restrict__ WtT) {
    __shared__ ushort Ls[64 * 136];
    const int bb = blockIdx.x, tid = threadIdx.x;
    if (bb < 32) {
        const int z = bb >> 4, pt = bb & 15;
        const int p0 = pt * 64;
        const float* Bz = B + z * NOPEN;
#pragma unroll
        for (int r = 0; r < 8; ++r) {
            int idx = r * 256 + tid;          // 128 ci x 16 p-chunks(4)
            int ci = idx >> 4, pq = idx & 15;
            float4 v = *(const float4*)&Zc[ci * NN + p0 + pq * 4];
            float bz = Bz[ci];
            Ls[(pq * 4 + 0) * 136 + ci] = f2bf(v.x + bz);
            Ls[(pq * 4 + 1) * 136 + ci] = f2bf(v.y + bz);
            Ls[(pq * 4 + 2) * 136 + ci] = f2bf(v.z + bz);
            Ls[(pq * 4 + 3) * 136 + ci] = f2bf(v.w + bz);
        }
        __syncthreads();
        ushort* Zz = Zct + z * (1032 * 128);
#pragma unroll
        for (int r = 0; r < 4; ++r) {
            int idx = r * 256 + tid;          // 64 rows x 16 chunks(8)
            int row = idx >> 4, ch = (idx & 15) * 8;
            *(bfrag*)&Zz[(p0 + row + 4) * 128 + ch] = *(const bfrag*)&Ls[row * 136 + ch];
        }
        if (pt == 0)  for (int idx = tid; idx < 4 * 128; idx += 256) Zz[idx] = 0;
        if (pt == 15) for (int idx = tid; idx < 4 * 128; idx += 256) Zz[1028 * 128 + idx] = 0;
    } else if (bb < 104) {
        int q = bb - 32;
        const int coq = q & 3; q >>= 2;
        const int t = q % 9, z = q / 9;
        const float* Wz = W + z * (NHID * NOPEN * KSZ);
        ushort* Wo = Wt + (size_t)(z * 9 + t) * NHID * NOPEN;
#pragma unroll
        for (int r = 0; r < 32; ++r) {
            int idx = r * 256 + tid;          // 64 co x 128 ci
            int co = coq * 64 + (idx >> 7), ci = idx & 127;
            Wo[co * NOPEN + ci] = f2bf(Wz[co * (NOPEN * KSZ) + ci * KSZ + t]);
        }
    } else {
        int q = bb - 104;
        const int ciq = q & 3; q >>= 2;
        const int t = q % 9, z = q / 9;
        const float* Wz = W + z * (NHID * NOPEN * KSZ);
        ushort* Wo = WtT + (size_t)(z * 9 + t) * NOPEN * NHID;
#pragma unroll
        for (int r = 0; r < 32; ++r) {
            int idx = r * 256 + tid;          // 32 ci x 256 co
            int ci = ciq * 32 + (idx >> 8), co = idx & 255;
            Wo[ci * NHID + co] = f2bf(Wz[co * (NOPEN * KSZ) + ci * KSZ + t]);
        }
    }
}

// ---------------- MFMA conv1d: C[co,p] = sum_{t,ci} Wt[t][co][ci] * Zct[p+t][ci] ----------------
// grid (16 p, 8 co, 2 z), block 256 = 4 waves (2co x 2p); block tile 32co x 64p; K = 9*128.
// single barrier: stage X halo tile (72x128) + all-tap W (9x32x128) in LDS, then 72 MFMA/wave.
__global__ __launch_bounds__(256) void k_conv(const ushort* __restrict__ Zct,
        const ushort* __restrict__ Wt, float* __restrict__ C0, ushort* __restrict__ C1b) {
    const int z = blockIdx.z;
    const int p0 = blockIdx.x * 64, co0 = blockIdx.y * 32;
    __shared__ ushort Xs[72 * 136];
    __shared__ ushort Wl[9 * 32 * 136];
    const int tid = threadIdx.x;
    const ushort* Zz = Zct + z * (1032 * 128);
    const ushort* Wz = Wt + (size_t)z * 9 * NHID * NOPEN;
    for (int idx = tid; idx < 1152; idx += 256) {       // 72 rows x 16 chunks
        int row = idx >> 4, ch = (idx & 15) * 8;
        *(bfrag*)&Xs[row * 136 + ch] = *(const bfrag*)&Zz[(p0 + row) * 128 + ch];
    }
    for (int idx = tid; idx < 4608; idx += 256) {       // 9t x 32co x 16 chunks
        int t = idx >> 9, rem = idx & 511;
        int c = rem >> 4, ch = (rem & 15) * 8;
        *(bfrag*)&Wl[(t * 32 + c) * 136 + ch] = *(const bfrag*)&Wz[(t * NHID + co0 + c) * 128 + ch];
    }
    __syncthreads();
    const int l = tid & 63, wv = tid >> 6;
    const int wm = wv >> 1, wn = wv & 1;
    const int lm = l & 15, lq = l >> 4;
    floatx4 acc[2] = {};
    for (int t = 0; t < 9; ++t) {
        const int wbase = (t * 32 + wm * 16 + lm) * 136 + lq * 8;
        const int xbase = (wn * 32 + lm + t) * 136 + lq * 8;
#pragma unroll
        for (int kc = 0; kc < 4; ++kc) {
            bfrag a = *(const bfrag*)&Wl[wbase + kc * 32];
            bfrag b0 = *(const bfrag*)&Xs[xbase + kc * 32];
            acc[0] = __builtin_amdgcn_mfma_f32_16x16x32_bf16(a, b0, acc[0], 0, 0, 0);
            bfrag b1 = *(const bfrag*)&Xs[xbase + 16 * 136 + kc * 32];
            acc[1] = __builtin_amdgcn_mfma_f32_16x16x32_bf16(a, b1, acc[1], 0, 0, 0);
        }
    }
    const int cog = co0 + wm * 16 + lq * 4;
    const int pg = p0 + wn * 32 + lm;
#pragma unroll
    for (int j = 0; j < 2; ++j)
#pragma unroll
        for (int r = 0; r < 4; ++r) {
            if (z == 0) C0[(cog + r) * NN + pg + j * 16] = acc[j][r];
            else        C1b[(cog + r) * NN + pg + j * 16] = f2bf(acc[j][r]);
        }
}

// ---------------- MFMA split-K GEMM: P[s] = X[:, sKc:(s+1)Kc] @ L[sKc:(s+1)Kc, :] ----------------
__global__ __launch_bounds__(256) void k_xl_mfma(const ushort* __restrict__ X,
                                                 const ushort* __restrict__ Lb,
                                                 float* __restrict__ P, int M) {
    __shared__ __align__(16) ushort As[64 * 136];
    __shared__ __align__(16) ushort Bs[128 * 136];
    const int tid = threadIdx.x;
    const int lane = tid & 63, wave = tid >> 6;
    const int wm = wave >> 1, wn = wave & 1;
    const int n0 = blockIdx.x * 128, m0 = blockIdx.y * 64, kc = blockIdx.z * 128;
    {
        int q = tid;
#pragma unroll
        for (int r = 0; r < 4; ++r, q += 256) {
            int row = q >> 4, ch = (q & 15) * 8;
            *(bfrag*)&As[row * 136 + ch] = *(const bfrag*)&X[(m0 + row) * NN + kc + ch];
        }
        q = tid;
#pragma unroll
        for (int r = 0; r < 8; ++r, q += 256) {
            int row = q >> 4, ch = (q & 15) * 8;
            *(bfrag*)&Bs[row * 136 + ch] = *(const bfrag*)&Lb[(n0 + row) * NN + kc + ch];
        }
    }
    __syncthreads();
    floatx4 acc[2][4] = {};
    const int lrow = (lane & 15) * 136;
    const int koff = (lane >> 4) * 8;
#pragma unroll
    for (int ks = 0; ks < 4; ++ks) {
        bfrag a[2], b[4];
#pragma unroll
        for (int i = 0; i < 2; ++i)
            a[i] = *(const bfrag*)&As[(wm * 32 + i * 16) * 136 + lrow + ks * 32 + koff];
#pragma unroll
        for (int j = 0; j < 4; ++j)
            b[j] = *(const bfrag*)&Bs[(wn * 64 + j * 16) * 136 + lrow + ks * 32 + koff];
#pragma unroll
        for (int i = 0; i < 2; ++i)
#pragma unroll
            for (int j = 0; j < 4; ++j)
                acc[i][j] = __builtin_amdgcn_mfma_f32_16x16x32_bf16(a[i], b[j], acc[i][j], 0, 0, 0);
    }
    const int mg0 = m0 + wm * 32 + (lane >> 4) * 4;
    const int ng0 = n0 + wn * 64 + (lane & 15);
    const size_t base = (size_t)blockIdx.z * M * NN;
#pragma unroll
    for (int i = 0; i < 2; ++i)
#pragma unroll
        for (int j = 0; j < 4; ++j)
#pragma unroll
            for (int r = 0; r < 4; ++r)
                P[base + (size_t)(mg0 + i * 16 + r) * NN + ng0 + j * 16] = acc[i][j][r];
}

// ---------------- instance norm stats; arr=1 also materializes A1sum = sum_s P1[s] ----------------
__global__ void k_inorm(const float* __restrict__ C0, const float* __restrict__ P1,
                        float* __restrict__ A1sum, float* __restrict__ Mu, float* __restrict__ Rs) {
    const int c = blockIdx.x, arr = blockIdx.y, tid = threadIdx.x;
    __shared__ float rs[4], rq[4];
    float4 v;
    if (arr == 0) {
        v = *(const float4*)&C0[c * NN + tid * 4];
    } else {
        v.x = v.y = v.z = v.w = 0.f;
#pragma unroll
        for (int s = 0; s < 8; ++s) {
            float4 p = *(const float4*)&P1[(size_t)(s * NHID + c) * NN + tid * 4];
            v.x += p.x; v.y += p.y; v.z += p.z; v.w += p.w;
        }
        *(float4*)&A1sum[c * NN + tid * 4] = v;
    }
    float s = (v.x + v.y) + (v.z + v.w);
    float q = (v.x * v.x + v.y * v.y) + (v.z * v.z + v.w * v.w);
#pragma unroll
    for (int off = 32; off > 0; off >>= 1) { s += __shfl_down(s, off); q += __shfl_down(q, off); }
    if ((tid & 63) == 0) { rs[tid >> 6] = s; rq[tid >> 6] = q; }
    __syncthreads();
    if (tid == 0) {
        float S = rs[0] + rs[1] + rs[2] + rs[3];
        float Q = rq[0] + rq[1] + rq[2] + rq[3];
        float mean = S * (1.f / NN);
        float var = Q * (1.f / NN) - mean * mean;
        Mu[arr * NHID + c] = mean;
        Rs[arr * NHID + c] = rsqrtf(var + IN_EPS);
    }
}

// ---------------- normalize + relu + bf16 + transpose -> At[pos+4][co], padded ----------------
// grid (16 p, 4 co64, 2 arr), block 256
__global__ __launch_bounds__(256) void k_normT(const float* __restrict__ C0,
        const float* __restrict__ A1sum, const float* __restrict__ Mu, const float* __restrict__ Rs,
        ushort* __restrict__ At0, ushort* __restrict__ At1) {
    const int arr = blockIdx.z;
    const int p0 = blockIdx.x * 64, co0 = blockIdx.y * 64;
    const float* in = arr ? A1sum : C0;
    ushort* out = arr ? At1 : At0;
    __shared__ ushort Ls[64 * 72];
    const int tid = threadIdx.x;
#pragma unroll
    for (int r = 0; r < 4; ++r) {
        int idx = r * 256 + tid;      // 64 co x 16 p-chunks(4)
        int col = idx >> 4, pq = idx & 15;
        int co = co0 + col;
        float4 v = *(const float4*)&in[co * NN + p0 + pq * 4];
        float m = Mu[arr * NHID + co], sc = Rs[arr * NHID + co];
        Ls[(pq * 4 + 0) * 72 + col] = f2bf(fmaxf((v.x - m) * sc, 0.f));
        Ls[(pq * 4 + 1) * 72 + col] = f2bf(fmaxf((v.y - m) * sc, 0.f));
        Ls[(pq * 4 + 2) * 72 + col] = f2bf(fmaxf((v.z - m) * sc, 0.f));
        Ls[(pq * 4 + 3) * 72 + col] = f2bf(fmaxf((v.w - m) * sc, 0.f));
    }
    __syncthreads();
#pragma unroll
    for (int r = 0; r < 2; ++r) {
        int idx = r * 256 + tid;      // 64 rows x 8 chunks(8)
        int row = idx >> 3, ch = (idx & 7) * 8;
        *(bfrag*)&out[(p0 + row + 4) * 256 + co0 + ch] = *(const bfrag*)&Ls[row * 72 + ch];
    }
    if (blockIdx.y == 0) {
        if (blockIdx.x == 0)  for (int idx = tid; idx < 4 * 256; idx += 256) out[idx] = 0;
        if (blockIdx.x == 15) for (int idx = tid; idx < 4 * 256; idx += 256) out[1028 * 256 + idx] = 0;
    }
}

// ---------------- MFMA convT: T[ci,p] = sum_{t,co} WtT[t][ci][co] * At[p+8-t][co] ----------------
// grid (16 p, 8 ci16, 2 z), block 256 = 4 waves (p quarters); block tile 16ci x 64p; K = 9*256.
__global__ __launch_bounds__(256) void k_convT(const ushort* __restrict__ At0,
        const ushort* __restrict__ At1, const ushort* __restrict__ WtT,
        float* __restrict__ T0, ushort* __restrict__ T1b) {
    const int z = blockIdx.z;
    const int p0 = blockIdx.x * 64, ci0 = blockIdx.y * 16;
    __shared__ ushort Al[72 * 264];
    __shared__ ushort Wl[9 * 16 * 264];
    const ushort* A = z ? At1 : At0;
    const ushort* Wz = WtT + (size_t)z * 9 * NOPEN * NHID;
    const int tid = threadIdx.x;
    for (int idx = tid; idx < 2304; idx += 256) {       // 72 rows x 32 chunks
        int row = idx >> 5, ch = (idx & 31) * 8;
        *(bfrag*)&Al[row * 264 + ch] = *(const bfrag*)&A[(p0 + row) * 256 + ch];
    }
    for (int idx = tid; idx < 4608; idx += 256) {       // 9t x 16ci x 32 chunks
        int t = idx >> 9, rem = idx & 511;
        int c = rem >> 5, ch = (rem & 31) * 8;
        *(bfrag*)&Wl[(t * 16 + c) * 264 + ch] = *(const bfrag*)&Wz[(t * NOPEN + ci0 + c) * 256 + ch];
    }
    __syncthreads();
    const int l = tid & 63, wv = tid >> 6;
    const int lm = l & 15, lq = l >> 4;
    floatx4 acc0 = {}, acc1 = {};
    for (int t = 0; t < 9; ++t) {
        const int abase = (wv * 16 + lm + 8 - t) * 264 + lq * 8;
        const int wbase = (t * 16 + lm) * 264 + lq * 8;
#pragma unroll
        for (int kc = 0; kc < 8; kc += 2) {
            bfrag a0 = *(const bfrag*)&Wl[wbase + kc * 32];
            bfrag b0 = *(const bfrag*)&Al[abase + kc * 32];
            acc0 = __builtin_amdgcn_mfma_f32_16x16x32_bf16(a0, b0, acc0, 0, 0, 0);
            bfrag a1 = *(const bfrag*)&Wl[wbase + kc * 32 + 32];
            bfrag b1 = *(const bfrag*)&Al[abase + kc * 32 + 32];
            acc1 = __builtin_amdgcn_mfma_f32_16x16x32_bf16(a1, b1, acc1, 0, 0, 0);
        }
    }
    floatx4 acc = acc0 + acc1;
    const int cig = ci0 + lq * 4;
    const int pg = p0 + wv * 16 + lm;
#pragma unroll
    for (int r = 0; r < 4; ++r) {
        if (z == 0) T0[(cig + r) * NN + pg] = acc[r];
        else        T1b[(cig + r) * NN + pg] = f2bf(acc[r]);
    }
}

// ---------------- leapfrog: Znew = 2 Zc - Zold - h^2 (T0 + sum_s P2[s]); writes into Zold ----------------
__global__ void k_leap(const float* __restrict__ P2, const float* __restrict__ T0,
                       const float* __restrict__ Zc, float* __restrict__ Zold) {
    int off = (blockIdx.x * 256 + threadIdx.x) * 4;
    float4 a = *(const float4*)&T0[off];
#pragma unroll
    for (int s = 0; s < 8; ++s) {
        float4 p = *(const float4*)&P2[(size_t)(s << 17) + off];
        a.x += p.x; a.y += p.y; a.z += p.z; a.w += p.w;
    }
    float4 zc = *(const float4*)&Zc[off];
    float4 zo = *(const float4*)&Zold[off];
    float4 zn;
    zn.x = 2.f * zc.x - zo.x - H2 * a.x;
    zn.y = 2.f * zc.y - zo.y - H2 * a.y;
    zn.z = 2.f * zc.z - zo.z - H2 * a.z;
    zn.w = 2.f * zc.w - zo.w - H2 * a.w;
    *(float4*)&Zold[off] = zn;
}

// ---------------- closing: out = concat(Kclose @ Zc, Kclose @ Zold) ----------------
__global__ void k_close(const float* __restrict__ Kclose, const float* __restrict__ Zc,
                        const float* __restrict__ Zold, float* __restrict__ out) {
    int n = blockIdx.x * 256 + threadIdx.x;
    int o = blockIdx.y;
    const float* Zb = blockIdx.z ? Zold : Zc;
    float a = 0.f;
#pragma unroll
    for (int c = 0; c < NOPEN; ++c) a = fmaf(Kclose[o * NOPEN + c], Zb[c * NN + n], a);
    out[blockIdx.z * (NCLOSE * NN) + o * NN + n] = a;
}

extern "C" void kernel_launch(void* const* d_in, const int* in_sizes, int n_in,
                              void* d_out, int out_size, void* d_ws, size_t ws_size,
                              hipStream_t stream) {
    const float* Z      = (const float*)d_in[0];
    const float* Kopen  = (const float*)d_in[1];
    const float* Kclose = (const float*)d_in[2];
    const float* W      = (const float*)d_in[3];
    const float* Bias   = (const float*)d_in[4];
    float* out = (float*)d_out;
    float* ws  = (float*)d_ws;

    // workspace layout (float units)
    float* Zb0   = ws + 0;          // 131072
    float* Zb1   = ws + 131072;     // 131072
    float* D2    = ws + 262144;     // 1048576
    float* C0    = ws + 1310720;    // 262144
    float* A1sum = ws + 1572864;    // 262144
    float* T0    = ws + 1835008;    // 131072
    float* P1    = ws + 1966080;    // 2097152
    float* P2    = ws + 4063232;    // 1048576
    float* sq    = ws + 5111808;    // 1024
    float* Dh    = ws + 5112832;    // 1024
    float* sig   = ws + 5113856;    // 1024
    float* Mu    = ws + 5114880;    // 1024 (2*256 used)
    float* Rs    = ws + 5115904;    // 1024
    ushort* Lb  = (ushort*)(ws + 5116928); // 1048576 us
    ushort* C1b = (ushort*)(ws + 5641216); // 262144 us
    ushort* T1b = (ushort*)(ws + 5772288); // 131072 us
    ushort* Zct = (ushort*)(ws + 5837824); // 2*1032*128 us
    ushort* Wt  = (ushort*)(ws + 5969920); // 2*9*256*128 us
    ushort* WtT = (ushort*)(ws + 6264832); // 2*9*128*256 us
    ushort* At0 = (ushort*)(ws + 6559744); // 1032*256 us
    ushort* At1 = (ushort*)(ws + 6691840); // 1032*256 us

    k_open<<<dim3(4, NOPEN), 256, 0, stream>>>(Kopen, Z, Zb0, Zb1);

    float* Zc = Zb0;
    float* Zold = Zb1;
    for (int i = 0; i < NLAYERS; ++i) {
        if (i % 10 == 0) {
            k_sq<<<dim3(4), 256, 0, stream>>>(Zc, sq, sig);
            k_d2<<<dim3(16, 32), 256, 0, stream>>>(Zc, sq, D2, sig);
            k_deg<<<dim3(NN), 256, 0, stream>>>(D2, sig, Dh);
            k_L<<<dim3(NN), 256, 0, stream>>>(D2, sig, Dh, Lb);
        }
        const float* Wl = W + (size_t)i * 2 * NHID * NOPEN * KSZ;
        const float* Bl = Bias + (size_t)i * 2 * NOPEN;

        k_prep<<<dim3(176), 256, 0, stream>>>(Zc, Wl, Bl, Zct, Wt, WtT);
        k_conv<<<dim3(16, 8, 2), 256, 0, stream>>>(Zct, Wt, C0, C1b);
        k_xl_mfma<<<dim3(8, 4, 8), 256, 0, stream>>>(C1b, Lb, P1, NHID);   // XL1
        k_inorm<<<dim3(NHID, 2), 256, 0, stream>>>(C0, P1, A1sum, Mu, Rs);
        k_normT<<<dim3(16, 4, 2), 256, 0, stream>>>(C0, A1sum, Mu, Rs, At0, At1);
        k_convT<<<dim3(16, 8, 2), 256, 0, stream>>>(At0, At1, WtT, T0, T1b);
        k_xl_mfma<<<dim3(8, 2, 8), 256, 0, stream>>>(T1b, Lb, P2, NOPEN);  // XL2
        k_leap<<<dim3(128), 256, 0, stream>>>(P2, T0, Zc, Zold);
        float* tmp = Zc; Zc = Zold; Zold = tmp;
    }

    k_close<<<dim3(4, NCLOSE, 2), 256, 0, stream>>>(Kclose, Zc, Zold, out);
}